// Round 2
// baseline (1232.838 us; speedup 1.0000x reference)
//
#include <hip/hip_runtime.h>
#include <hip/hip_bf16.h>
#include <math.h>

// Problem constants (fixed by the reference)
#define MM 1024      // checks
#define NN 2048      // vars
#define DVv 3
#define DCc 6
#define DD 8
#define BB 128       // batch
#define TT 5         // iterations
#define CINc 48      // DC*D
#define VINv 25      // DV*D+1
#define HCc 192      // 4*CIN
#define HVv 100      // 4*VIN
#define EE 6144      // M*DC == N*DV edges

__device__ __forceinline__ float gelu_exact(float x) {
    return 0.5f * x * (1.0f + erff(x * 0.70710678118654752f));
}

// ---------------------------------------------------------------------------
// Check MLP: one block per check m, one thread per batch row b.
// x[48] in regs, y[48] in regs. Weights staged to LDS in 2 chunks of 96
// hidden cols; w1 staged TRANSPOSED ([t][i], pitch 52 floats so rows stay
// 16B-aligned for float4 broadcast reads).
// ---------------------------------------------------------------------------
__global__ __launch_bounds__(128)
void chk_kernel(const float* __restrict__ chk_w1, const float* __restrict__ chk_b1,
                const float* __restrict__ chk_w2, const float* __restrict__ chk_b2,
                const int* __restrict__ syndromes, const int* __restrict__ chk_nbrs,
                const int* __restrict__ v2c_gather, const float* __restrict__ prior_llr,
                const float* __restrict__ v2c_buf,   // [E][B][D], var-edge order
                float* __restrict__ c2v_buf,         // [E][B][D], check-edge order
                int first)
{
    const int m = blockIdx.x;
    const int b = threadIdx.x;   // 0..127

    __shared__ float w1s[96 * 52];   // transposed chunk [t][i], pitch 52 (16B-aligned rows)
    __shared__ float w2s[96 * 48];   // [t][o]
    __shared__ float b1s[96];

    // ---- load x[48] (this check's incoming messages) ----
    float x[CINc];
    if (first) {
        #pragma unroll
        for (int s = 0; s < DCc; ++s) {
            int nb = chk_nbrs[m * DCc + s];
            float p = prior_llr[nb];
            x[s * DD + 0] = p;
            #pragma unroll
            for (int d = 1; d < DD; ++d) x[s * DD + d] = 0.0f;
        }
    } else {
        #pragma unroll
        for (int s = 0; s < DCc; ++s) {
            int e = v2c_gather[m * DCc + s];
            const float* src = v2c_buf + ((size_t)e * BB + b) * DD;
            float4 v0 = *(const float4*)(src);
            float4 v1 = *(const float4*)(src + 4);
            x[s*DD+0]=v0.x; x[s*DD+1]=v0.y; x[s*DD+2]=v0.z; x[s*DD+3]=v0.w;
            x[s*DD+4]=v1.x; x[s*DD+5]=v1.y; x[s*DD+6]=v1.z; x[s*DD+7]=v1.w;
        }
    }

    float y[CINc];
    #pragma unroll
    for (int o = 0; o < CINc; ++o) y[o] = chk_b2[m * CINc + o];

    for (int chunk = 0; chunk < 2; ++chunk) {
        const int t0 = chunk * 96;
        __syncthreads();   // protect LDS reuse from previous chunk
        // stage w1 chunk transposed: global idx k = i*96 + tt (coalesced within rows)
        for (int k = threadIdx.x; k < CINc * 96; k += 128) {
            int i = k / 96, tt = k % 96;
            w1s[tt * 52 + i] = chk_w1[((size_t)m * CINc + i) * HCc + t0 + tt];
        }
        // stage w2 chunk as-is (fully contiguous)
        for (int k = threadIdx.x; k < 96 * CINc; k += 128) {
            w2s[k] = chk_w2[((size_t)m * HCc + t0) * CINc + k];
        }
        for (int k = threadIdx.x; k < 96; k += 128) {
            b1s[k] = chk_b1[(size_t)m * HCc + t0 + k];
        }
        __syncthreads();

        for (int tt = 0; tt < 96; ++tt) {
            float ht = b1s[tt];
            const float4* w1r = (const float4*)(w1s + tt * 52);
            #pragma unroll
            for (int j = 0; j < 12; ++j) {
                float4 w = w1r[j];
                ht += x[4*j+0]*w.x + x[4*j+1]*w.y + x[4*j+2]*w.z + x[4*j+3]*w.w;
            }
            float g = gelu_exact(ht);
            const float4* w2r = (const float4*)(w2s + tt * 48);
            #pragma unroll
            for (int j = 0; j < 12; ++j) {
                float4 w = w2r[j];
                y[4*j+0] += g*w.x; y[4*j+1] += g*w.y; y[4*j+2] += g*w.z; y[4*j+3] += g*w.w;
            }
        }
    }

    // syndrome sign flip, then scatter to check-edge-ordered buffer (coalesced 32B/lane)
    const float sgn = (float)(1 - 2 * syndromes[(size_t)b * MM + m]);
    #pragma unroll
    for (int s = 0; s < DCc; ++s) {
        float* dst = c2v_buf + (((size_t)(m * DCc + s)) * BB + b) * DD;
        float4 v0, v1;
        v0.x=y[s*DD+0]*sgn; v0.y=y[s*DD+1]*sgn; v0.z=y[s*DD+2]*sgn; v0.w=y[s*DD+3]*sgn;
        v1.x=y[s*DD+4]*sgn; v1.y=y[s*DD+5]*sgn; v1.z=y[s*DD+6]*sgn; v1.w=y[s*DD+7]*sgn;
        *(float4*)dst       = v0;
        *(float4*)(dst + 4) = v1;
    }
}

// ---------------------------------------------------------------------------
// Variable MLP: one block per var n, one thread per batch row b.
// x[25], y[25] in regs; full weights staged to LDS once (w1 transposed,
// both padded to pitch 28 floats = 112B, 16B-aligned).
// ---------------------------------------------------------------------------
__global__ __launch_bounds__(128)
void var_kernel(const float* __restrict__ var_w1, const float* __restrict__ var_b1,
                const float* __restrict__ var_w2, const float* __restrict__ var_b2,
                const int* __restrict__ c2v_gather, const float* __restrict__ prior_llr,
                const float* __restrict__ c2v_buf,   // [E][B][D], check-edge order
                float* __restrict__ v2c_buf,         // [E][B][D], var-edge order
                float* __restrict__ llr_out)         // d_out + step*B*N, layout [B][N], fp32
{
    const int n = blockIdx.x;
    const int b = threadIdx.x;

    __shared__ float w1s[HVv * 28];  // transposed [t][i], pitch 28
    __shared__ float w2s[HVv * 28];  // [t][o], pitch 28
    __shared__ float b1s[HVv];

    // stage w1 transposed: global k = i*100 + t contiguous
    for (int k = threadIdx.x; k < VINv * HVv; k += 128) {
        int i = k / HVv, t = k % HVv;
        w1s[t * 28 + i] = var_w1[(size_t)n * VINv * HVv + k];
    }
    // stage w2 with pitch pad: global k = t*25 + o contiguous
    for (int k = threadIdx.x; k < HVv * VINv; k += 128) {
        int t = k / VINv, o = k % VINv;
        w2s[t * 28 + o] = var_w2[(size_t)n * HVv * VINv + k];
    }
    for (int k = threadIdx.x; k < HVv; k += 128) {
        b1s[k] = var_b1[(size_t)n * HVv + k];
    }

    // ---- load x[25] ----
    float x[VINv];
    #pragma unroll
    for (int l = 0; l < DVv; ++l) {
        int p = c2v_gather[n * DVv + l];
        const float* src = c2v_buf + ((size_t)p * BB + b) * DD;
        float4 v0 = *(const float4*)(src);
        float4 v1 = *(const float4*)(src + 4);
        x[l*DD+0]=v0.x; x[l*DD+1]=v0.y; x[l*DD+2]=v0.z; x[l*DD+3]=v0.w;
        x[l*DD+4]=v1.x; x[l*DD+5]=v1.y; x[l*DD+6]=v1.z; x[l*DD+7]=v1.w;
    }
    x[24] = prior_llr[n];

    float y[VINv];
    #pragma unroll
    for (int o = 0; o < VINv; ++o) y[o] = var_b2[(size_t)n * VINv + o];

    __syncthreads();

    for (int t = 0; t < HVv; ++t) {
        float ht = b1s[t];
        const float4* w1r = (const float4*)(w1s + t * 28);
        #pragma unroll
        for (int j = 0; j < 6; ++j) {
            float4 w = w1r[j];
            ht += x[4*j+0]*w.x + x[4*j+1]*w.y + x[4*j+2]*w.z + x[4*j+3]*w.w;
        }
        ht += x[24] * w1s[t * 28 + 24];
        float g = gelu_exact(ht);
        const float4* w2r = (const float4*)(w2s + t * 28);
        #pragma unroll
        for (int j = 0; j < 6; ++j) {
            float4 w = w2r[j];
            y[4*j+0] += g*w.x; y[4*j+1] += g*w.y; y[4*j+2] += g*w.z; y[4*j+3] += g*w.w;
        }
        y[24] += g * w2s[t * 28 + 24];
    }

    // LLR output (fp32), layout [B][N] within this step's slab
    llr_out[(size_t)b * NN + n] = y[24];

    // messages out, var-edge order (coalesced 32B/lane)
    #pragma unroll
    for (int l = 0; l < DVv; ++l) {
        float* dst = v2c_buf + (((size_t)(n * DVv + l)) * BB + b) * DD;
        float4 v0, v1;
        v0.x=y[l*DD+0]; v0.y=y[l*DD+1]; v0.z=y[l*DD+2]; v0.w=y[l*DD+3];
        v1.x=y[l*DD+4]; v1.y=y[l*DD+5]; v1.z=y[l*DD+6]; v1.w=y[l*DD+7];
        *(float4*)dst       = v0;
        *(float4*)(dst + 4) = v1;
    }
}

extern "C" void kernel_launch(void* const* d_in, const int* in_sizes, int n_in,
                              void* d_out, int out_size, void* d_ws, size_t ws_size,
                              hipStream_t stream) {
    const int*   syndromes = (const int*)  d_in[0];
    const float* prior_llr = (const float*)d_in[1];
    const float* chk_w1    = (const float*)d_in[2];
    const float* chk_b1    = (const float*)d_in[3];
    const float* chk_w2    = (const float*)d_in[4];
    const float* chk_b2    = (const float*)d_in[5];
    const float* var_w1    = (const float*)d_in[6];
    const float* var_b1    = (const float*)d_in[7];
    const float* var_w2    = (const float*)d_in[8];
    const float* var_b2    = (const float*)d_in[9];
    const int*   chk_nbrs  = (const int*)  d_in[10];
    const int*   c2v_g     = (const int*)  d_in[11];
    const int*   v2c_g     = (const int*)  d_in[12];

    float* out = (float*)d_out;

    // workspace: two [E][B][D] fp32 message buffers (25.2 MB each)
    float* c2v = (float*)d_ws;
    float* v2c = c2v + (size_t)EE * BB * DD;

    for (int t = 0; t < TT; ++t) {
        chk_kernel<<<MM, 128, 0, stream>>>(chk_w1, chk_b1, chk_w2, chk_b2,
                                           syndromes, chk_nbrs, v2c_g, prior_llr,
                                           v2c, c2v, (t == 0) ? 1 : 0);
        var_kernel<<<NN, 128, 0, stream>>>(var_w1, var_b1, var_w2, var_b2,
                                           c2v_g, prior_llr,
                                           c2v, v2c,
                                           out + (size_t)t * BB * NN);
    }
}

// Round 4
// 602.710 us; speedup vs baseline: 2.0455x; 2.0455x over previous
//
#include <hip/hip_runtime.h>
#include <math.h>

#define MM 1024      // checks
#define NN 2048      // vars
#define BB 128       // batch
#define TT 5         // iterations
#define EE 6144      // edges

typedef __bf16 bf16x8 __attribute__((ext_vector_type(8)));
typedef float  f32x4  __attribute__((ext_vector_type(4)));
typedef unsigned int u32x4 __attribute__((ext_vector_type(4)));

__device__ __forceinline__ float gelu_exact(float x) {
    return 0.5f * x * (1.0f + erff(x * 0.70710678118654752f));
}

// ---------------------------------------------------------------------------
// init: v2c[e][b][0..7] = {bf16(prior[e/3]), 0,...}  (t=0 check input)
// ---------------------------------------------------------------------------
__global__ __launch_bounds__(256)
void init_kernel(const float* __restrict__ prior, __bf16* __restrict__ v2c)
{
    int idx = blockIdx.x * 256 + threadIdx.x;     // e*128 + b
    int e = idx >> 7;
    bf16x8 v;
    #pragma unroll
    for (int j = 0; j < 8; ++j) v[j] = (__bf16)0.0f;
    v[0] = (__bf16)prior[e / 3];
    *(bf16x8*)(v2c + (size_t)idx * 8) = v;
}

// ---------------------------------------------------------------------------
// Check MLP via MFMA. One block (4 waves) per check; wave handles batch tiles
// {w*16, 64+w*16}. X:[128x48] W1:[48x192] W2:[192x48].
// MFMA 16x16x32 bf16: A[m=l&15][k=q*8+j], B[k=q*8+j][n=l&15],
// C/D[row=q*4+r][col=l&15]   (m89/m91/m120-verified layouts)
// ---------------------------------------------------------------------------
__global__ __launch_bounds__(256, 2)
void chk_kernel(const float* __restrict__ w1g, const float* __restrict__ b1g,
                const float* __restrict__ w2g, const float* __restrict__ b2g,
                const int* __restrict__ syndromes,
                const int* __restrict__ v2c_gather,
                const __bf16* __restrict__ v2c, __bf16* __restrict__ c2v)
{
    const int m = blockIdx.x;
    const int tid = threadIdx.x;
    const int w = tid >> 6, l = tid & 63, q = l >> 4, c = l & 15;

    // fragment-sequential weight layouts: frag(kt,nt) at ((kt*NT+nt)*64+lane)*8+j
    __shared__ __align__(16) __bf16 w1f[24 * 512];   // kt=0..1, nt=0..11 (K pad 64)
    __shared__ __align__(16) __bf16 w2f[18 * 512];   // kt=0..5, nt=0..2  (K=192 exact)
    __shared__ __align__(16) __bf16 hb[4 * 3200];    // per-wave 16x200 scratch
    __shared__ float b1s[192];
    __shared__ float b2s[48];
    __shared__ float sgns[128];
    __shared__ int   eg[6];

    // zero the kt=1 half of w1f (covers k=48..63 pad)
    {
        u32x4* zp = (u32x4*)(w1f + 12 * 512);
        for (int i = tid; i < 768; i += 256) zp[i] = (u32x4){0, 0, 0, 0};
    }
    __syncthreads();

    // stage W1 (coalesced fp32 reads, bf16 fragment-layout LDS writes)
    for (int idx = tid; idx < 48 * 192; idx += 256) {
        int k = idx / 192, n = idx % 192;
        float v = w1g[(size_t)m * (48 * 192) + idx];
        int kt = k >> 5, qq = (k & 31) >> 3, j = k & 7;
        int nt = n >> 4, cc = n & 15;
        w1f[((kt * 12 + nt) * 64 + qq * 16 + cc) * 8 + j] = (__bf16)v;
    }
    for (int idx = tid; idx < 192 * 48; idx += 256) {
        int k = idx / 48, n = idx % 48;
        float v = w2g[(size_t)m * (192 * 48) + idx];
        int kt = k >> 5, qq = (k & 31) >> 3, j = k & 7;
        int nt = n >> 4, cc = n & 15;
        w2f[((kt * 3 + nt) * 64 + qq * 16 + cc) * 8 + j] = (__bf16)v;
    }
    if (tid < 192) b1s[tid] = b1g[(size_t)m * 192 + tid];
    if (tid < 48)  b2s[tid] = b2g[(size_t)m * 48 + tid];
    if (tid < 128) sgns[tid] = (float)(1 - 2 * syndromes[(size_t)tid * MM + m]);
    if (tid < 6)   eg[tid] = v2c_gather[m * 6 + tid];
    __syncthreads();

    __bf16* myh = hb + w * 3200;    // H tile (pitch 200) and Y tile (pitch 72) overlap — safe:
                                    // H pad cols never read; H fully rewritten each tile.
    const int e0 = eg[q];
    const int e1 = (q < 2) ? eg[4 + q] : 0;

    for (int t2 = 0; t2 < 2; ++t2) {
        const int bt = t2 * 64 + w * 16;

        // ---- layer 1: A direct from global (16B per lane), B from w1f ----
        bf16x8 a0 = *(const bf16x8*)(v2c + ((size_t)e0 * BB + bt + c) * 8);
        bf16x8 a1;
        #pragma unroll
        for (int j = 0; j < 8; ++j) a1[j] = (__bf16)0.0f;
        if (q < 2) a1 = *(const bf16x8*)(v2c + ((size_t)e1 * BB + bt + c) * 8);

        f32x4 acc[12];
        #pragma unroll
        for (int nt = 0; nt < 12; ++nt) {
            bf16x8 bf0 = *(const bf16x8*)(w1f + (nt * 64 + l) * 8);
            bf16x8 bf1 = *(const bf16x8*)(w1f + ((12 + nt) * 64 + l) * 8);
            f32x4 z = {0.f, 0.f, 0.f, 0.f};
            z = __builtin_amdgcn_mfma_f32_16x16x32_bf16(a0, bf0, z, 0, 0, 0);
            z = __builtin_amdgcn_mfma_f32_16x16x32_bf16(a1, bf1, z, 0, 0, 0);
            acc[nt] = z;
        }

        // bias + GELU -> H tile (pitch 200), C-layout -> [row][k]
        #pragma unroll
        for (int nt = 0; nt < 12; ++nt) {
            #pragma unroll
            for (int r = 0; r < 4; ++r) {
                int row = q * 4 + r, col = nt * 16 + c;
                float h = acc[nt][r] + b1s[col];
                myh[row * 200 + col] = (__bf16)gelu_exact(h);
            }
        }
        __syncthreads();

        // ---- layer 2: A from H tile (A-layout reads), B from w2f ----
        f32x4 acc2[3];
        #pragma unroll
        for (int nt = 0; nt < 3; ++nt) acc2[nt] = (f32x4){0.f, 0.f, 0.f, 0.f};
        #pragma unroll
        for (int kt = 0; kt < 6; ++kt) {
            bf16x8 a = *(const bf16x8*)(myh + c * 200 + kt * 32 + q * 8);
            #pragma unroll
            for (int nt = 0; nt < 3; ++nt) {
                bf16x8 bfr = *(const bf16x8*)(w2f + ((kt * 3 + nt) * 64 + l) * 8);
                acc2[nt] = __builtin_amdgcn_mfma_f32_16x16x32_bf16(a, bfr, acc2[nt], 0, 0, 0);
            }
        }
        __syncthreads();

        // ---- epilogue: bias + syndrome sign -> Y tile (pitch 72) ----
        #pragma unroll
        for (int nt = 0; nt < 3; ++nt) {
            #pragma unroll
            for (int r = 0; r < 4; ++r) {
                int row = q * 4 + r, col = nt * 16 + c;
                float yv = (acc2[nt][r] + b2s[col]) * sgns[bt + row];
                myh[row * 72 + col] = (__bf16)yv;
            }
        }
        __syncthreads();

        // coalesced 16B message stores: 96 chunks (s=0..5, row=0..15)
        {
            int s = l >> 4, row = l & 15;
            u32x4 vv = *(const u32x4*)(myh + row * 72 + s * 8);
            *(u32x4*)(c2v + ((size_t)(m * 6 + s) * BB + bt + row) * 8) = vv;
            if (l < 32) {
                int s2 = (64 + l) >> 4, row2 = l & 15;
                u32x4 v2 = *(const u32x4*)(myh + row2 * 72 + s2 * 8);
                *(u32x4*)(c2v + ((size_t)(m * 6 + s2) * BB + bt + row2) * 8) = v2;
            }
        }
        __syncthreads();
    }
}

// ---------------------------------------------------------------------------
// Variable MLP via MFMA. One block (4 waves) per var. X:[128x25] W1:[25x100]
// W2:[100x25]. K pads: 25->32 (layer1), 100->128 (layer2); N pads 100->112,
// 25->32, all pad regions zeroed so MFMA contributions are exact 0.
// ---------------------------------------------------------------------------
__global__ __launch_bounds__(256, 4)
void var_kernel(const float* __restrict__ w1g, const float* __restrict__ b1g,
                const float* __restrict__ w2g, const float* __restrict__ b2g,
                const int* __restrict__ c2v_gather, const float* __restrict__ prior,
                const __bf16* __restrict__ c2v, __bf16* __restrict__ v2c,
                float* __restrict__ llr_out)
{
    const int nv = blockIdx.x;
    const int tid = threadIdx.x;
    const int w = tid >> 6, l = tid & 63, q = l >> 4, c = l & 15;

    __shared__ __align__(16) __bf16 w1vf[7 * 512];   // kt=0, nt=0..6
    __shared__ __align__(16) __bf16 w2vf[8 * 512];   // kt=0..3, nt=0..1
    __shared__ __align__(16) __bf16 hb[4 * 2816];    // per-wave: 16x136 H + 16x40 Y
    __shared__ float b1s[112];
    __shared__ float b2s[32];
    __shared__ int   cgs[3];

    // zero-fill all padded LDS regions
    {
        u32x4* zp = (u32x4*)w1vf;
        for (int i = tid; i < 448; i += 256) zp[i] = (u32x4){0, 0, 0, 0};
        u32x4* zp2 = (u32x4*)w2vf;
        for (int i = tid; i < 512; i += 256) zp2[i] = (u32x4){0, 0, 0, 0};
        u32x4* zp3 = (u32x4*)hb;
        for (int i = tid; i < 1408; i += 256) zp3[i] = (u32x4){0, 0, 0, 0};
    }
    __syncthreads();

    for (int idx = tid; idx < 25 * 100; idx += 256) {
        int k = idx / 100, n = idx % 100;
        float v = w1g[(size_t)nv * (25 * 100) + idx];
        int qq = k >> 3, j = k & 7, nt = n >> 4, cc = n & 15;
        w1vf[(nt * 64 + qq * 16 + cc) * 8 + j] = (__bf16)v;
    }
    for (int idx = tid; idx < 100 * 25; idx += 256) {
        int k = idx / 25, n = idx % 25;
        float v = w2g[(size_t)nv * (100 * 25) + idx];
        int kt = k >> 5, qq = (k & 31) >> 3, j = k & 7, nt = n >> 4, cc = n & 15;
        w2vf[((kt * 2 + nt) * 64 + qq * 16 + cc) * 8 + j] = (__bf16)v;
    }
    if (tid < 112) b1s[tid] = (tid < 100) ? b1g[(size_t)nv * 100 + tid] : 0.0f;
    if (tid < 32)  b2s[tid] = (tid < 25) ? b2g[(size_t)nv * 25 + tid] : 0.0f;
    if (tid < 3)   cgs[tid] = c2v_gather[nv * 3 + tid];
    __syncthreads();

    __bf16* myh = hb + w * 2816;          // H: 16 rows, pitch 136 (cols 112..127 stay 0)
    __bf16* myy = hb + w * 2816 + 2176;   // Y: 16 rows, pitch 40 (separate: keep H pad intact)
    const float pr = prior[nv];
    const __bf16 prbf = (__bf16)pr;
    const int ep = (q < 3) ? cgs[q] : 0;

    for (int t2 = 0; t2 < 2; ++t2) {
        const int bt = t2 * 64 + w * 16;

        // ---- layer 1 A-frag: q<3 = message slots, q==3 = {prior,0...} ----
        bf16x8 a;
        #pragma unroll
        for (int j = 0; j < 8; ++j) a[j] = (__bf16)0.0f;
        if (q < 3) {
            a = *(const bf16x8*)(c2v + ((size_t)ep * BB + bt + c) * 8);
        } else {
            a[0] = prbf;
        }

        f32x4 acc[7];
        #pragma unroll
        for (int nt = 0; nt < 7; ++nt) {
            bf16x8 bfr = *(const bf16x8*)(w1vf + (nt * 64 + l) * 8);
            f32x4 z = {0.f, 0.f, 0.f, 0.f};
            acc[nt] = __builtin_amdgcn_mfma_f32_16x16x32_bf16(a, bfr, z, 0, 0, 0);
        }

        #pragma unroll
        for (int nt = 0; nt < 7; ++nt) {
            #pragma unroll
            for (int r = 0; r < 4; ++r) {
                int row = q * 4 + r, col = nt * 16 + c;    // col<=111; b1s pad=0, W1 pad=0 -> gelu(0)=0
                float h = acc[nt][r] + b1s[col];
                myh[row * 136 + col] = (__bf16)gelu_exact(h);
            }
        }
        __syncthreads();

        // ---- layer 2 ----
        f32x4 acc2[2];
        acc2[0] = (f32x4){0.f, 0.f, 0.f, 0.f};
        acc2[1] = (f32x4){0.f, 0.f, 0.f, 0.f};
        #pragma unroll
        for (int kt = 0; kt < 4; ++kt) {
            bf16x8 a2 = *(const bf16x8*)(myh + c * 136 + kt * 32 + q * 8);
            #pragma unroll
            for (int nt = 0; nt < 2; ++nt) {
                bf16x8 bfr = *(const bf16x8*)(w2vf + ((kt * 2 + nt) * 64 + l) * 8);
                acc2[nt] = __builtin_amdgcn_mfma_f32_16x16x32_bf16(a2, bfr, acc2[nt], 0, 0, 0);
            }
        }
        __syncthreads();

        // ---- epilogue: bias; col<24 -> message, col==24 -> fp32 LLR ----
        #pragma unroll
        for (int nt = 0; nt < 2; ++nt) {
            #pragma unroll
            for (int r = 0; r < 4; ++r) {
                int row = q * 4 + r, col = nt * 16 + c;
                float yv = acc2[nt][r] + b2s[col];
                if (col < 24) myy[row * 40 + col] = (__bf16)yv;
                else if (col == 24) llr_out[(size_t)(bt + row) * NN + nv] = yv;
            }
        }
        __syncthreads();

        // coalesced 16B message stores: 48 chunks (s=0..2, row=0..15)
        if (l < 48) {
            int s = l >> 4, row = l & 15;
            u32x4 vv = *(const u32x4*)(myy + row * 40 + s * 8);
            *(u32x4*)(v2c + ((size_t)(nv * 3 + s) * BB + bt + row) * 8) = vv;
        }
        __syncthreads();
    }
}

extern "C" void kernel_launch(void* const* d_in, const int* in_sizes, int n_in,
                              void* d_out, int out_size, void* d_ws, size_t ws_size,
                              hipStream_t stream) {
    const int*   syndromes = (const int*)  d_in[0];
    const float* prior_llr = (const float*)d_in[1];
    const float* chk_w1    = (const float*)d_in[2];
    const float* chk_b1    = (const float*)d_in[3];
    const float* chk_w2    = (const float*)d_in[4];
    const float* chk_b2    = (const float*)d_in[5];
    const float* var_w1    = (const float*)d_in[6];
    const float* var_b1    = (const float*)d_in[7];
    const float* var_w2    = (const float*)d_in[8];
    const float* var_b2    = (const float*)d_in[9];
    const int*   c2v_g     = (const int*)  d_in[11];
    const int*   v2c_g     = (const int*)  d_in[12];

    float* out = (float*)d_out;

    __bf16* v2c = (__bf16*)d_ws;                       // [E][B][8] bf16, 12.6 MB
    __bf16* c2v = v2c + (size_t)EE * BB * 8;           // [E][B][8] bf16, 12.6 MB

    init_kernel<<<EE * BB / 256, 256, 0, stream>>>(prior_llr, v2c);

    for (int t = 0; t < TT; ++t) {
        chk_kernel<<<MM, 256, 0, stream>>>(chk_w1, chk_b1, chk_w2, chk_b2,
                                           syndromes, v2c_g, v2c, c2v);
        var_kernel<<<NN, 256, 0, stream>>>(var_w1, var_b1, var_w2, var_b2,
                                           c2v_g, prior_llr, c2v, v2c,
                                           out + (size_t)t * BB * NN);
    }
}

// Round 5
// 475.218 us; speedup vs baseline: 2.5943x; 1.2683x over previous
//
#include <hip/hip_runtime.h>
#include <math.h>

#define MM 1024      // checks
#define NN 2048      // vars
#define BB 128       // batch
#define TT 5         // iterations
#define EE 6144      // edges

typedef __bf16 bf16x8 __attribute__((ext_vector_type(8)));
typedef float  f32x4  __attribute__((ext_vector_type(4)));
typedef unsigned int u32x4 __attribute__((ext_vector_type(4)));

// Abramowitz-Stegun 7.1.26 erf (|eps| < 1.5e-7) -> exact-GELU within fp32 noise
__device__ __forceinline__ float gelu_fast(float x) {
    float xe = x * 0.70710678118654752f;
    float ax = fabsf(xe);
    float t  = __builtin_amdgcn_rcpf(1.0f + 0.3275911f * ax);
    float p  = t * (0.254829592f + t * (-0.284496736f + t * (1.421413741f +
               t * (-1.453152027f + t * 1.061405429f))));
    float er = 1.0f - p * __expf(-xe * xe);
    er = copysignf(er, xe);
    return 0.5f * x * (1.0f + er);
}

// wave-level LDS fence: H/Y tiles are wave-private; ds ops complete in order
// per wave, so lgkmcnt(0) + compiler memory barrier suffices (no s_barrier).
__device__ __forceinline__ void wave_lds_fence() {
    asm volatile("s_waitcnt lgkmcnt(0)" ::: "memory");
}

// ---------------------------------------------------------------------------
// init: v2c[e][b][0..7] = {bf16(prior[e/3]), 0,...}  (t=0 check input)
// ---------------------------------------------------------------------------
__global__ __launch_bounds__(256)
void init_kernel(const float* __restrict__ prior, __bf16* __restrict__ v2c)
{
    int idx = blockIdx.x * 256 + threadIdx.x;     // e*128 + b
    int e = idx >> 7;
    bf16x8 v;
    #pragma unroll
    for (int j = 0; j < 8; ++j) v[j] = (__bf16)0.0f;
    v[0] = (__bf16)prior[e / 3];
    *(bf16x8*)(v2c + (size_t)idx * 8) = v;
}

// ---------------------------------------------------------------------------
// prep: weights fp32 -> bf16 in MFMA fragment-sequential layout (once/launch).
// chk: 42 fragments/check (w1: f=kt*12+nt, 24; w2: f=24+kt*3+nt, 18)
// fragment chunk for lane l at (f*64+l)*8 + j ; element (k,n):
//   k = kt*32 + (l>>4)*8 + j ; n = nt*16 + (l&15) ; pads zeroed.
// ---------------------------------------------------------------------------
__global__ __launch_bounds__(256)
void prep_chk(const float* __restrict__ w1g, const float* __restrict__ w2g,
              __bf16* __restrict__ wchk)
{
    const int m = blockIdx.x;
    const int tid = threadIdx.x, w = tid >> 6, l = tid & 63, qq = l >> 4, cc = l & 15;
    const float* s1 = w1g + (size_t)m * (48 * 192);
    const float* s2 = w2g + (size_t)m * (192 * 48);
    __bf16* dst = wchk + (size_t)m * 21504;
    for (int f = w; f < 42; f += 4) {
        bf16x8 v;
        if (f < 24) {
            int kt = f / 12, nt = f % 12;
            #pragma unroll
            for (int j = 0; j < 8; ++j) {
                int k = kt * 32 + qq * 8 + j, n = nt * 16 + cc;
                v[j] = (k < 48) ? (__bf16)s1[k * 192 + n] : (__bf16)0.0f;
            }
        } else {
            int g = f - 24, kt = g / 3, nt = g % 3;
            #pragma unroll
            for (int j = 0; j < 8; ++j) {
                int k = kt * 32 + qq * 8 + j, n = nt * 16 + cc;
                v[j] = (__bf16)s2[k * 48 + n];
            }
        }
        *(bf16x8*)(dst + f * 512 + l * 8) = v;
    }
}

// var: 15 fragments/var (w1: f=nt, 7; w2: f=7+kt*2+nt, 8); pads zeroed.
__global__ __launch_bounds__(256)
void prep_var(const float* __restrict__ w1g, const float* __restrict__ w2g,
              __bf16* __restrict__ wvar)
{
    const int nv = blockIdx.x;
    const int tid = threadIdx.x, w = tid >> 6, l = tid & 63, qq = l >> 4, cc = l & 15;
    const float* s1 = w1g + (size_t)nv * (25 * 100);
    const float* s2 = w2g + (size_t)nv * (100 * 25);
    __bf16* dst = wvar + (size_t)nv * 7680;
    for (int f = w; f < 15; f += 4) {
        bf16x8 v;
        if (f < 7) {
            int nt = f;
            #pragma unroll
            for (int j = 0; j < 8; ++j) {
                int k = qq * 8 + j, n = nt * 16 + cc;
                v[j] = (k < 25 && n < 100) ? (__bf16)s1[k * 100 + n] : (__bf16)0.0f;
            }
        } else {
            int g = f - 7, kt = g >> 1, nt = g & 1;
            #pragma unroll
            for (int j = 0; j < 8; ++j) {
                int k = kt * 32 + qq * 8 + j, n = nt * 16 + cc;
                v[j] = (k < 100 && n < 25) ? (__bf16)s2[k * 25 + n] : (__bf16)0.0f;
            }
        }
        *(bf16x8*)(dst + f * 512 + l * 8) = v;
    }
}

// ---------------------------------------------------------------------------
// Check MLP via MFMA. One block (4 waves) per check; wave handles batch tiles
// {w*16, 64+w*16}. X:[128x48] W1:[48x192] W2:[192x48].
// MFMA 16x16x32 bf16: A[m=l&15][k=q*8+j], B[k=q*8+j][n=l&15],
// C/D[row=q*4+r][col=l&15]
// ---------------------------------------------------------------------------
__global__ __launch_bounds__(256, 2)
void chk_kernel(const __bf16* __restrict__ wchk,
                const float* __restrict__ b1g, const float* __restrict__ b2g,
                const int* __restrict__ syndromes,
                const int* __restrict__ v2c_gather,
                const __bf16* __restrict__ v2c, __bf16* __restrict__ c2v)
{
    const int m = blockIdx.x;
    const int tid = threadIdx.x;
    const int w = tid >> 6, l = tid & 63, q = l >> 4, c = l & 15;

    __shared__ __align__(16) __bf16 wAll[42 * 512];  // w1f: f<24, w2f: f>=24
    __shared__ __align__(16) __bf16 hb[4 * 3200];    // per-wave 16x200 scratch
    __shared__ float b1s[192];
    __shared__ float b2s[48];
    __shared__ float sgns[128];
    __shared__ int   eg[6];

    // stage prepped weights: pure 16B stride-1 copies (conflict-free)
    {
        const __bf16* wsrc = wchk + (size_t)m * 21504;
        for (int f = w; f < 42; f += 4) {
            u32x4 v = *(const u32x4*)(wsrc + f * 512 + l * 8);
            *(u32x4*)(wAll + f * 512 + l * 8) = v;
        }
    }
    if (tid < 192) b1s[tid] = b1g[(size_t)m * 192 + tid];
    if (tid < 48)  b2s[tid] = b2g[(size_t)m * 48 + tid];
    if (tid < 128) sgns[tid] = (float)(1 - 2 * syndromes[(size_t)tid * MM + m]);
    if (tid < 6)   eg[tid] = v2c_gather[m * 6 + tid];
    __syncthreads();

    const __bf16* w1f = wAll;
    const __bf16* w2f = wAll + 24 * 512;
    __bf16* myh = hb + w * 3200;    // H (pitch 200) / Y (pitch 72) overlap, wave-private
    const int e0 = eg[q];
    const int e1 = (q < 2) ? eg[4 + q] : 0;

    for (int t2 = 0; t2 < 2; ++t2) {
        const int bt = t2 * 64 + w * 16;

        // ---- layer 1: A direct from global, B from LDS fragments ----
        bf16x8 a0 = *(const bf16x8*)(v2c + ((size_t)e0 * BB + bt + c) * 8);
        bf16x8 a1;
        #pragma unroll
        for (int j = 0; j < 8; ++j) a1[j] = (__bf16)0.0f;
        if (q < 2) a1 = *(const bf16x8*)(v2c + ((size_t)e1 * BB + bt + c) * 8);

        f32x4 acc[12];
        #pragma unroll
        for (int nt = 0; nt < 12; ++nt) {
            bf16x8 bf0 = *(const bf16x8*)(w1f + (nt * 64 + l) * 8);
            bf16x8 bf1 = *(const bf16x8*)(w1f + ((12 + nt) * 64 + l) * 8);
            f32x4 z = {0.f, 0.f, 0.f, 0.f};
            z = __builtin_amdgcn_mfma_f32_16x16x32_bf16(a0, bf0, z, 0, 0, 0);
            z = __builtin_amdgcn_mfma_f32_16x16x32_bf16(a1, bf1, z, 0, 0, 0);
            acc[nt] = z;
        }

        // bias + GELU -> H tile (pitch 200), C-layout -> [row][k]
        #pragma unroll
        for (int nt = 0; nt < 12; ++nt) {
            #pragma unroll
            for (int r = 0; r < 4; ++r) {
                int row = q * 4 + r, col = nt * 16 + c;
                float h = acc[nt][r] + b1s[col];
                myh[row * 200 + col] = (__bf16)gelu_fast(h);
            }
        }
        wave_lds_fence();

        // ---- layer 2: A from H tile (A-layout reads), B from w2f ----
        f32x4 acc2[3];
        #pragma unroll
        for (int nt = 0; nt < 3; ++nt) acc2[nt] = (f32x4){0.f, 0.f, 0.f, 0.f};
        #pragma unroll
        for (int kt = 0; kt < 6; ++kt) {
            bf16x8 a = *(const bf16x8*)(myh + c * 200 + kt * 32 + q * 8);
            #pragma unroll
            for (int nt = 0; nt < 3; ++nt) {
                bf16x8 bfr = *(const bf16x8*)(w2f + ((kt * 3 + nt) * 64 + l) * 8);
                acc2[nt] = __builtin_amdgcn_mfma_f32_16x16x32_bf16(a, bfr, acc2[nt], 0, 0, 0);
            }
        }
        wave_lds_fence();

        // ---- epilogue: bias + syndrome sign -> Y tile (pitch 72) ----
        #pragma unroll
        for (int nt = 0; nt < 3; ++nt) {
            #pragma unroll
            for (int r = 0; r < 4; ++r) {
                int row = q * 4 + r, col = nt * 16 + c;
                float yv = (acc2[nt][r] + b2s[col]) * sgns[bt + row];
                myh[row * 72 + col] = (__bf16)yv;
            }
        }
        wave_lds_fence();

        // coalesced 16B message stores: 96 chunks (s=0..5, row=0..15)
        {
            int s = l >> 4, row = l & 15;
            u32x4 vv = *(const u32x4*)(myh + row * 72 + s * 8);
            *(u32x4*)(c2v + ((size_t)(m * 6 + s) * BB + bt + row) * 8) = vv;
            if (l < 32) {
                int s2 = (64 + l) >> 4, row2 = l & 15;
                u32x4 v2 = *(const u32x4*)(myh + row2 * 72 + s2 * 8);
                *(u32x4*)(c2v + ((size_t)(m * 6 + s2) * BB + bt + row2) * 8) = v2;
            }
        }
        wave_lds_fence();   // WAR: Y reads above vs next-iter H writes
    }
}

// ---------------------------------------------------------------------------
// Variable MLP via MFMA. One block (4 waves) per var. X:[128x25] W1:[25x100]
// W2:[100x25]. Pads zeroed by prep; H pad cols zeroed once below.
// ---------------------------------------------------------------------------
__global__ __launch_bounds__(256, 4)
void var_kernel(const __bf16* __restrict__ wvar,
                const float* __restrict__ b1g, const float* __restrict__ b2g,
                const int* __restrict__ c2v_gather, const float* __restrict__ prior,
                const __bf16* __restrict__ c2v, __bf16* __restrict__ v2c,
                float* __restrict__ llr_out)
{
    const int nv = blockIdx.x;
    const int tid = threadIdx.x;
    const int w = tid >> 6, l = tid & 63, q = l >> 4, c = l & 15;

    __shared__ __align__(16) __bf16 wAll[15 * 512];  // w1vf: f<7, w2vf: f>=7
    __shared__ __align__(16) __bf16 hb[4 * 2816];    // per-wave: 16x136 H + 16x40 Y
    __shared__ float b1s[112];
    __shared__ float b2s[32];
    __shared__ int   cgs[3];

    // zero hb once (H cols 112..127 are read as layer-2 A k=112..127; weights
    // there are zero but stale LDS could be bf16-NaN -> 0*NaN=NaN. Zero it.)
    {
        u32x4* zp = (u32x4*)hb;
        for (int i = tid; i < 1408; i += 256) zp[i] = (u32x4){0, 0, 0, 0};
    }
    {
        const __bf16* wsrc = wvar + (size_t)nv * 7680;
        for (int f = w; f < 15; f += 4) {
            u32x4 v = *(const u32x4*)(wsrc + f * 512 + l * 8);
            *(u32x4*)(wAll + f * 512 + l * 8) = v;
        }
    }
    if (tid < 112) b1s[tid] = (tid < 100) ? b1g[(size_t)nv * 100 + tid] : 0.0f;
    if (tid < 32)  b2s[tid] = (tid < 25) ? b2g[(size_t)nv * 25 + tid] : 0.0f;
    if (tid < 3)   cgs[tid] = c2v_gather[nv * 3 + tid];
    __syncthreads();

    const __bf16* w1vf = wAll;
    const __bf16* w2vf = wAll + 7 * 512;
    __bf16* myh = hb + w * 2816;          // H: 16 rows, pitch 136
    __bf16* myy = hb + w * 2816 + 2176;   // Y: 16 rows, pitch 40
    const float pr = prior[nv];
    const __bf16 prbf = (__bf16)pr;
    const int ep = (q < 3) ? cgs[q] : 0;

    for (int t2 = 0; t2 < 2; ++t2) {
        const int bt = t2 * 64 + w * 16;

        // ---- layer 1 A-frag: q<3 = message slots, q==3 = {prior,0...} ----
        bf16x8 a;
        #pragma unroll
        for (int j = 0; j < 8; ++j) a[j] = (__bf16)0.0f;
        if (q < 3) {
            a = *(const bf16x8*)(c2v + ((size_t)ep * BB + bt + c) * 8);
        } else {
            a[0] = prbf;
        }

        f32x4 acc[7];
        #pragma unroll
        for (int nt = 0; nt < 7; ++nt) {
            bf16x8 bfr = *(const bf16x8*)(w1vf + (nt * 64 + l) * 8);
            f32x4 z = {0.f, 0.f, 0.f, 0.f};
            acc[nt] = __builtin_amdgcn_mfma_f32_16x16x32_bf16(a, bfr, z, 0, 0, 0);
        }

        #pragma unroll
        for (int nt = 0; nt < 7; ++nt) {
            #pragma unroll
            for (int r = 0; r < 4; ++r) {
                int row = q * 4 + r, col = nt * 16 + c;
                float h = acc[nt][r] + b1s[col];
                myh[row * 136 + col] = (__bf16)gelu_fast(h);
            }
        }
        wave_lds_fence();

        // ---- layer 2 ----
        f32x4 acc2[2];
        acc2[0] = (f32x4){0.f, 0.f, 0.f, 0.f};
        acc2[1] = (f32x4){0.f, 0.f, 0.f, 0.f};
        #pragma unroll
        for (int kt = 0; kt < 4; ++kt) {
            bf16x8 a2 = *(const bf16x8*)(myh + c * 136 + kt * 32 + q * 8);
            #pragma unroll
            for (int nt = 0; nt < 2; ++nt) {
                bf16x8 bfr = *(const bf16x8*)(w2vf + ((kt * 2 + nt) * 64 + l) * 8);
                acc2[nt] = __builtin_amdgcn_mfma_f32_16x16x32_bf16(a2, bfr, acc2[nt], 0, 0, 0);
            }
        }
        wave_lds_fence();

        // ---- epilogue: bias; col<24 -> message, col==24 -> fp32 LLR ----
        #pragma unroll
        for (int nt = 0; nt < 2; ++nt) {
            #pragma unroll
            for (int r = 0; r < 4; ++r) {
                int row = q * 4 + r, col = nt * 16 + c;
                float yv = acc2[nt][r] + b2s[col];
                if (col < 24) myy[row * 40 + col] = (__bf16)yv;
                else if (col == 24) llr_out[(size_t)(bt + row) * NN + nv] = yv;
            }
        }
        wave_lds_fence();

        // coalesced 16B message stores: 48 chunks (s=0..2, row=0..15)
        if (l < 48) {
            int s = l >> 4, row = l & 15;
            u32x4 vv = *(const u32x4*)(myy + row * 40 + s * 8);
            *(u32x4*)(v2c + ((size_t)(nv * 3 + s) * BB + bt + row) * 8) = vv;
        }
        wave_lds_fence();   // WAR: Y reads above vs next-iter writes
    }
}

extern "C" void kernel_launch(void* const* d_in, const int* in_sizes, int n_in,
                              void* d_out, int out_size, void* d_ws, size_t ws_size,
                              hipStream_t stream) {
    const int*   syndromes = (const int*)  d_in[0];
    const float* prior_llr = (const float*)d_in[1];
    const float* chk_w1    = (const float*)d_in[2];
    const float* chk_b1    = (const float*)d_in[3];
    const float* chk_w2    = (const float*)d_in[4];
    const float* chk_b2    = (const float*)d_in[5];
    const float* var_w1    = (const float*)d_in[6];
    const float* var_b1    = (const float*)d_in[7];
    const float* var_w2    = (const float*)d_in[8];
    const float* var_b2    = (const float*)d_in[9];
    const int*   c2v_g     = (const int*)  d_in[11];
    const int*   v2c_g     = (const int*)  d_in[12];

    float* out = (float*)d_out;

    // workspace layout (bf16): v2c | c2v | wchk | wvar  (~100.6 MB total)
    __bf16* v2c  = (__bf16*)d_ws;                          // 6144*128*8
    __bf16* c2v  = v2c + (size_t)EE * BB * 8;              // 6144*128*8
    __bf16* wchk = c2v + (size_t)EE * BB * 8;              // 1024*21504
    __bf16* wvar = wchk + (size_t)MM * 21504;              // 2048*7680

    prep_chk<<<MM, 256, 0, stream>>>(chk_w1, chk_w2, wchk);
    prep_var<<<NN, 256, 0, stream>>>(var_w1, var_w2, wvar);
    init_kernel<<<EE * BB / 256, 256, 0, stream>>>(prior_llr, v2c);

    for (int t = 0; t < TT; ++t) {
        chk_kernel<<<MM, 256, 0, stream>>>(wchk, chk_b1, chk_b2,
                                           syndromes, v2c_g, v2c, c2v);
        var_kernel<<<NN, 256, 0, stream>>>(wvar, var_b1, var_b2,
                                           c2v_g, prior_llr, c2v, v2c,
                                           out + (size_t)t * BB * NN);
    }
}

// Round 6
// 443.808 us; speedup vs baseline: 2.7779x; 1.0708x over previous
//
#include <hip/hip_runtime.h>
#include <math.h>

#define MM 1024      // checks
#define NN 2048      // vars
#define BB 128       // batch
#define TT 5         // iterations
#define EE 6144      // edges

typedef __bf16 bf16x8 __attribute__((ext_vector_type(8)));
typedef float  f32x4  __attribute__((ext_vector_type(4)));
typedef unsigned int u32x4 __attribute__((ext_vector_type(4)));
typedef unsigned int u32x2 __attribute__((ext_vector_type(2)));

// Abramowitz-Stegun 7.1.26 erf (|eps| < 1.5e-7) -> exact-GELU within fp32 noise
__device__ __forceinline__ float gelu_fast(float x) {
    float xe = x * 0.70710678118654752f;
    float ax = fabsf(xe);
    float t  = __builtin_amdgcn_rcpf(1.0f + 0.3275911f * ax);
    float p  = t * (0.254829592f + t * (-0.284496736f + t * (1.421413741f +
               t * (-1.453152027f + t * 1.061405429f))));
    float er = 1.0f - p * __expf(-xe * xe);
    er = copysignf(er, xe);
    return 0.5f * x * (1.0f + er);
}

// wave-level LDS fence: tiles are wave-private; DS ops are in-order per wave,
// lgkmcnt(0) + compiler barrier orders write->read round trips.
__device__ __forceinline__ void wave_lds_fence() {
    asm volatile("s_waitcnt lgkmcnt(0)" ::: "memory");
}

// ---------------------------------------------------------------------------
// init: v2c[e][b][0..7] = {bf16(prior[e/3]), 0,...}  (t=0 check input)
// ---------------------------------------------------------------------------
__global__ __launch_bounds__(256)
void init_kernel(const float* __restrict__ prior, __bf16* __restrict__ v2c)
{
    int idx = blockIdx.x * 256 + threadIdx.x;     // e*128 + b
    int e = idx >> 7;
    bf16x8 v;
    #pragma unroll
    for (int j = 0; j < 8; ++j) v[j] = (__bf16)0.0f;
    v[0] = (__bf16)prior[e / 3];
    *(bf16x8*)(v2c + (size_t)idx * 8) = v;
}

// ---------------------------------------------------------------------------
// prep_all: fp32 weights -> bf16 MFMA fragment-sequential layout, fused for
// chk+var, ONE WAVE PER FRAGMENT (73728 waves = 18432 blocks — full GPU).
// chk frag f (42/check): f<24 -> w1 (kt=f/12, nt=f%12, K pad 48->64);
//                        f>=24 -> w2 (g=f-24, kt=g/3, nt=g%3, K=192 exact).
// var frag f (15/var):   f<7  -> w1 (nt=f, K pad 25->32, N pad 100->112);
//                        f>=7 -> w2 (g=f-7, kt=g>>1, nt=g&1, K pad 100->128).
// element j of lane l: k = kt*32 + (l>>4)*8 + j ; n = nt*16 + (l&15).
// ---------------------------------------------------------------------------
__global__ __launch_bounds__(256)
void prep_all(const float* __restrict__ cw1, const float* __restrict__ cw2,
              const float* __restrict__ vw1, const float* __restrict__ vw2,
              __bf16* __restrict__ wchk, __bf16* __restrict__ wvar)
{
    const int wid = blockIdx.x * 4 + (threadIdx.x >> 6);
    const int l = threadIdx.x & 63, qq = l >> 4, cc = l & 15;
    bf16x8 v;
    __bf16* dst;
    if (wid < MM * 42) {
        const int m = wid / 42, f = wid % 42;
        if (f < 24) {
            const int kt = f / 12, nt = f % 12;
            const float* s1 = cw1 + (size_t)m * (48 * 192);
            #pragma unroll
            for (int j = 0; j < 8; ++j) {
                int k = kt * 32 + qq * 8 + j;
                v[j] = (k < 48) ? (__bf16)s1[k * 192 + nt * 16 + cc] : (__bf16)0.0f;
            }
        } else {
            const int g = f - 24, kt = g / 3, nt = g % 3;
            const float* s2 = cw2 + (size_t)m * (192 * 48);
            #pragma unroll
            for (int j = 0; j < 8; ++j) {
                int k = kt * 32 + qq * 8 + j;
                v[j] = (__bf16)s2[k * 48 + nt * 16 + cc];
            }
        }
        dst = wchk + (size_t)m * 21504 + (f * 64 + l) * 8;
    } else {
        const int tsk = wid - MM * 42;
        const int nv = tsk / 15, f = tsk % 15;
        if (f < 7) {
            const float* s1 = vw1 + (size_t)nv * (25 * 100);
            #pragma unroll
            for (int j = 0; j < 8; ++j) {
                int k = qq * 8 + j, n = f * 16 + cc;
                v[j] = (k < 25 && n < 100) ? (__bf16)s1[k * 100 + n] : (__bf16)0.0f;
            }
        } else {
            const int g = f - 7, kt = g >> 1, nt = g & 1;
            const float* s2 = vw2 + (size_t)nv * (100 * 25);
            #pragma unroll
            for (int j = 0; j < 8; ++j) {
                int k = kt * 32 + qq * 8 + j, n = nt * 16 + cc;
                v[j] = (k < 100 && n < 25) ? (__bf16)s2[k * 25 + n] : (__bf16)0.0f;
            }
        }
        dst = wvar + (size_t)nv * 7680 + (f * 64 + l) * 8;
    }
    *(bf16x8*)dst = v;
}

// ---------------------------------------------------------------------------
// Check MLP. One block (4 waves) per check, wave-independent (NO barriers).
// B-fragments read directly from prepped global (16B/lane, L2-broadcast
// across the 4 waves). LDS = wave-private H/Y scratch only (25.6 KB).
// MFMA 16x16x32 bf16: A[m=l&15][k=q*8+j], B[k=q*8+j][n=l&15],
// C/D[row=q*4+r][col=l&15]
// ---------------------------------------------------------------------------
__global__ __launch_bounds__(256, 4)
void chk_kernel(const __bf16* __restrict__ wchk,
                const float* __restrict__ b1g, const float* __restrict__ b2g,
                const int* __restrict__ syndromes,
                const int* __restrict__ v2c_gather,
                const __bf16* __restrict__ v2c, __bf16* __restrict__ c2v)
{
    const int m = blockIdx.x;
    const int tid = threadIdx.x;
    const int w = tid >> 6, l = tid & 63, q = l >> 4, c = l & 15;

    __shared__ __align__(16) __bf16 hb[4 * 3200];
    __bf16* myh = hb + w * 3200;      // H (pitch 200) / Y (pitch 72) overlap; wave-private

    const __bf16* wb = wchk + (size_t)m * 21504;

    // hoisted per-lane biases and syndrome signs
    float b1v[12], b2v[3], sg[8];
    #pragma unroll
    for (int nt = 0; nt < 12; ++nt) b1v[nt] = b1g[(size_t)m * 192 + nt * 16 + c];
    #pragma unroll
    for (int nt = 0; nt < 3; ++nt)  b2v[nt] = b2g[(size_t)m * 48 + nt * 16 + c];
    #pragma unroll
    for (int t2 = 0; t2 < 2; ++t2)
        #pragma unroll
        for (int r = 0; r < 4; ++r) {
            int row = t2 * 64 + w * 16 + q * 4 + r;
            sg[t2 * 4 + r] = (float)(1 - 2 * syndromes[(size_t)row * MM + m]);
        }

    const int e0 = v2c_gather[m * 6 + q];
    const int e1 = (q < 2) ? v2c_gather[m * 6 + 4 + q] : 0;

    for (int t2 = 0; t2 < 2; ++t2) {
        const int bt = t2 * 64 + w * 16;

        // ---- layer 1 ----
        bf16x8 a0 = *(const bf16x8*)(v2c + ((size_t)e0 * BB + bt + c) * 8);
        bf16x8 a1;
        #pragma unroll
        for (int j = 0; j < 8; ++j) a1[j] = (__bf16)0.0f;
        if (q < 2) a1 = *(const bf16x8*)(v2c + ((size_t)e1 * BB + bt + c) * 8);

        f32x4 acc[12];
        #pragma unroll
        for (int nt = 0; nt < 12; ++nt) {
            bf16x8 bf0 = *(const bf16x8*)(wb + (nt * 64 + l) * 8);
            bf16x8 bf1 = *(const bf16x8*)(wb + ((12 + nt) * 64 + l) * 8);
            f32x4 z = {0.f, 0.f, 0.f, 0.f};
            z = __builtin_amdgcn_mfma_f32_16x16x32_bf16(a0, bf0, z, 0, 0, 0);
            z = __builtin_amdgcn_mfma_f32_16x16x32_bf16(a1, bf1, z, 0, 0, 0);
            acc[nt] = z;
        }

        // bias + GELU -> H (C-layout -> [row][k])
        #pragma unroll
        for (int nt = 0; nt < 12; ++nt) {
            #pragma unroll
            for (int r = 0; r < 4; ++r) {
                int row = q * 4 + r;
                myh[row * 200 + nt * 16 + c] = (__bf16)gelu_fast(acc[nt][r] + b1v[nt]);
            }
        }
        wave_lds_fence();

        // ---- layer 2 ----
        f32x4 acc2[3];
        #pragma unroll
        for (int nt = 0; nt < 3; ++nt) acc2[nt] = (f32x4){0.f, 0.f, 0.f, 0.f};
        #pragma unroll
        for (int kt = 0; kt < 6; ++kt) {
            bf16x8 a = *(const bf16x8*)(myh + c * 200 + kt * 32 + q * 8);
            #pragma unroll
            for (int nt = 0; nt < 3; ++nt) {
                bf16x8 bfr = *(const bf16x8*)(wb + ((24 + kt * 3 + nt) * 64 + l) * 8);
                acc2[nt] = __builtin_amdgcn_mfma_f32_16x16x32_bf16(a, bfr, acc2[nt], 0, 0, 0);
            }
        }
        wave_lds_fence();

        // ---- epilogue: bias + syndrome sign -> Y (pitch 72) ----
        #pragma unroll
        for (int nt = 0; nt < 3; ++nt) {
            #pragma unroll
            for (int r = 0; r < 4; ++r) {
                int row = q * 4 + r;
                myh[row * 72 + nt * 16 + c] = (__bf16)((acc2[nt][r] + b2v[nt]) * sg[t2 * 4 + r]);
            }
        }
        wave_lds_fence();

        // coalesced 16B message stores: 96 chunks (s=0..5, row=0..15)
        {
            int s = l >> 4, row = l & 15;
            u32x4 vv = *(const u32x4*)(myh + row * 72 + s * 8);
            *(u32x4*)(c2v + ((size_t)(m * 6 + s) * BB + bt + row) * 8) = vv;
            if (l < 32) {
                int s2 = 4 + (l >> 4), row2 = l & 15;
                u32x4 v2 = *(const u32x4*)(myh + row2 * 72 + s2 * 8);
                *(u32x4*)(c2v + ((size_t)(m * 6 + s2) * BB + bt + row2) * 8) = v2;
            }
        }
        wave_lds_fence();   // Y reads above vs next-t2 H writes (WAR)
    }
}

// ---------------------------------------------------------------------------
// Variable MLP. One block (4 waves) per var, wave-independent (NO barriers).
// ---------------------------------------------------------------------------
__global__ __launch_bounds__(256, 4)
void var_kernel(const __bf16* __restrict__ wvar,
                const float* __restrict__ b1g, const float* __restrict__ b2g,
                const int* __restrict__ c2v_gather, const float* __restrict__ prior,
                const __bf16* __restrict__ c2v, __bf16* __restrict__ v2c,
                float* __restrict__ llr_out, int last)
{
    const int nv = blockIdx.x;
    const int tid = threadIdx.x;
    const int w = tid >> 6, l = tid & 63, q = l >> 4, c = l & 15;

    __shared__ __align__(16) __bf16 hb[4 * 2816];
    __bf16* myh = hb + w * 2816;          // H: 16 rows, pitch 136
    __bf16* myy = myh + 2176;             // Y: 16 rows, pitch 40 (disjoint from H)

    const __bf16* wb = wvar + (size_t)nv * 7680;

    // zero H pad cols 112..127 (read as layer-2 A k=112..127; weights there are
    // zero but 0*NaN=NaN from stale LDS). Wave-private: 16 rows x 16 cols.
    {
        int r = l >> 2, g = l & 3;
        *(u32x2*)(myh + r * 136 + 112 + g * 4) = (u32x2){0, 0};
    }

    float b1v[7], b2v[2];
    #pragma unroll
    for (int nt = 0; nt < 7; ++nt) {
        int col = nt * 16 + c;
        b1v[nt] = (col < 100) ? b1g[(size_t)nv * 100 + col] : 0.0f;
    }
    #pragma unroll
    for (int nt = 0; nt < 2; ++nt) {
        int col = nt * 16 + c;
        b2v[nt] = (col < 25) ? b2g[(size_t)nv * 25 + col] : 0.0f;
    }
    const __bf16 prbf = (__bf16)prior[nv];
    const int ep = (q < 3) ? c2v_gather[nv * 3 + q] : 0;

    for (int t2 = 0; t2 < 2; ++t2) {
        const int bt = t2 * 64 + w * 16;

        // ---- layer 1 A-frag: q<3 = message slots, q==3 = {prior,0...} ----
        bf16x8 a;
        #pragma unroll
        for (int j = 0; j < 8; ++j) a[j] = (__bf16)0.0f;
        if (q < 3) a = *(const bf16x8*)(c2v + ((size_t)ep * BB + bt + c) * 8);
        else       a[0] = prbf;

        f32x4 acc[7];
        #pragma unroll
        for (int nt = 0; nt < 7; ++nt) {
            bf16x8 bfr = *(const bf16x8*)(wb + (nt * 64 + l) * 8);
            f32x4 z = {0.f, 0.f, 0.f, 0.f};
            acc[nt] = __builtin_amdgcn_mfma_f32_16x16x32_bf16(a, bfr, z, 0, 0, 0);
        }

        #pragma unroll
        for (int nt = 0; nt < 7; ++nt) {
            #pragma unroll
            for (int r = 0; r < 4; ++r) {
                int row = q * 4 + r;
                myh[row * 136 + nt * 16 + c] = (__bf16)gelu_fast(acc[nt][r] + b1v[nt]);
            }
        }
        wave_lds_fence();

        // ---- layer 2 ----
        f32x4 acc2[2];
        acc2[0] = (f32x4){0.f, 0.f, 0.f, 0.f};
        acc2[1] = (f32x4){0.f, 0.f, 0.f, 0.f};
        #pragma unroll
        for (int kt = 0; kt < 4; ++kt) {
            bf16x8 a2 = *(const bf16x8*)(myh + c * 136 + kt * 32 + q * 8);
            #pragma unroll
            for (int nt = 0; nt < 2; ++nt) {
                bf16x8 bfr = *(const bf16x8*)(wb + ((7 + kt * 2 + nt) * 64 + l) * 8);
                acc2[nt] = __builtin_amdgcn_mfma_f32_16x16x32_bf16(a2, bfr, acc2[nt], 0, 0, 0);
            }
        }
        wave_lds_fence();

        // ---- epilogue: bias; col<24 -> message, col==24 -> fp32 LLR ----
        #pragma unroll
        for (int nt = 0; nt < 2; ++nt) {
            #pragma unroll
            for (int r = 0; r < 4; ++r) {
                int row = q * 4 + r, col = nt * 16 + c;
                float yv = acc2[nt][r] + b2v[nt];
                if (col < 24) myy[row * 40 + col] = (__bf16)yv;
                else if (col == 24) llr_out[(size_t)(bt + row) * NN + nv] = yv;
            }
        }
        wave_lds_fence();

        // coalesced 16B message stores (skipped on last iteration: dead data)
        if (!last && l < 48) {
            int s = l >> 4, row = l & 15;
            u32x4 vv = *(const u32x4*)(myy + row * 40 + s * 8);
            *(u32x4*)(v2c + ((size_t)(nv * 3 + s) * BB + bt + row) * 8) = vv;
        }
        wave_lds_fence();   // WAR vs next-t2 writes
    }
}

extern "C" void kernel_launch(void* const* d_in, const int* in_sizes, int n_in,
                              void* d_out, int out_size, void* d_ws, size_t ws_size,
                              hipStream_t stream) {
    const int*   syndromes = (const int*)  d_in[0];
    const float* prior_llr = (const float*)d_in[1];
    const float* chk_w1    = (const float*)d_in[2];
    const float* chk_b1    = (const float*)d_in[3];
    const float* chk_w2    = (const float*)d_in[4];
    const float* chk_b2    = (const float*)d_in[5];
    const float* var_w1    = (const float*)d_in[6];
    const float* var_b1    = (const float*)d_in[7];
    const float* var_w2    = (const float*)d_in[8];
    const float* var_b2    = (const float*)d_in[9];
    const int*   c2v_g     = (const int*)  d_in[11];
    const int*   v2c_g     = (const int*)  d_in[12];

    float* out = (float*)d_out;

    // workspace layout (bf16): v2c | c2v | wchk | wvar  (~100.7 MB total)
    __bf16* v2c  = (__bf16*)d_ws;                          // 6144*128*8
    __bf16* c2v  = v2c + (size_t)EE * BB * 8;              // 6144*128*8
    __bf16* wchk = c2v + (size_t)EE * BB * 8;              // 1024*21504
    __bf16* wvar = wchk + (size_t)MM * 21504;              // 2048*7680

    prep_all<<<(MM * 42 + NN * 15) / 4, 256, 0, stream>>>(chk_w1, chk_w2,
                                                          var_w1, var_w2,
                                                          wchk, wvar);
    init_kernel<<<EE * BB / 256, 256, 0, stream>>>(prior_llr, v2c);

    for (int t = 0; t < TT; ++t) {
        chk_kernel<<<MM, 256, 0, stream>>>(wchk, chk_b1, chk_b2,
                                           syndromes, v2c_g, v2c, c2v);
        var_kernel<<<NN, 256, 0, stream>>>(wvar, var_b1, var_b2,
                                           c2v_g, prior_llr, c2v, v2c,
                                           out + (size_t)t * BB * NN,
                                           (t == TT - 1) ? 1 : 0);
    }
}

// Round 7
// 416.315 us; speedup vs baseline: 2.9613x; 1.0660x over previous
//
#include <hip/hip_runtime.h>
#include <math.h>

#define MM 1024      // checks
#define NN 2048      // vars
#define BB 128       // batch
#define TT 5         // iterations
#define EE 6144      // edges

typedef __bf16 bf16x8 __attribute__((ext_vector_type(8)));
typedef float  f32x4  __attribute__((ext_vector_type(4)));
typedef unsigned int u32x4 __attribute__((ext_vector_type(4)));
typedef unsigned int u32x2 __attribute__((ext_vector_type(2)));

// Abramowitz-Stegun 7.1.26 erf (|eps| < 1.5e-7)
__device__ __forceinline__ float gelu_fast(float x) {
    float xe = x * 0.70710678118654752f;
    float ax = fabsf(xe);
    float t  = __builtin_amdgcn_rcpf(1.0f + 0.3275911f * ax);
    float p  = t * (0.254829592f + t * (-0.284496736f + t * (1.421413741f +
               t * (-1.453152027f + t * 1.061405429f))));
    float er = 1.0f - p * __expf(-xe * xe);
    er = copysignf(er, xe);
    return 0.5f * x * (1.0f + er);
}

// wave-private LDS round-trip fence (DS ops are in-order per wave)
__device__ __forceinline__ void wave_lds_fence() {
    asm volatile("s_waitcnt lgkmcnt(0)" ::: "memory");
}

__global__ __launch_bounds__(256)
void init_kernel(const float* __restrict__ prior, __bf16* __restrict__ v2c)
{
    int idx = blockIdx.x * 256 + threadIdx.x;     // e*128 + b
    int e = idx >> 7;
    bf16x8 v;
    #pragma unroll
    for (int j = 0; j < 8; ++j) v[j] = (__bf16)0.0f;
    v[0] = (__bf16)prior[e / 3];
    *(bf16x8*)(v2c + (size_t)idx * 8) = v;
}

// ---------------------------------------------------------------------------
// prep_all: fp32 -> bf16 fragment-sequential. One wave per fragment.
// CLAMP-THEN-SELECT so all 8 gather loads are unconditional (hoistable).
// ---------------------------------------------------------------------------
__global__ __launch_bounds__(256)
void prep_all(const float* __restrict__ cw1, const float* __restrict__ cw2,
              const float* __restrict__ vw1, const float* __restrict__ vw2,
              __bf16* __restrict__ wchk, __bf16* __restrict__ wvar)
{
    const int wid = blockIdx.x * 4 + (threadIdx.x >> 6);
    const int l = threadIdx.x & 63, qq = l >> 4, cc = l & 15;
    float tmp[8];
    bf16x8 v;
    __bf16* dst;
    if (wid < MM * 42) {
        const int m = wid / 42, f = wid % 42;
        if (f < 24) {
            const int kt = f / 12, nt = f % 12;
            const float* s1 = cw1 + (size_t)m * (48 * 192);
            #pragma unroll
            for (int j = 0; j < 8; ++j) {
                int k = kt * 32 + qq * 8 + j;
                tmp[j] = s1[min(k, 47) * 192 + nt * 16 + cc];
            }
            #pragma unroll
            for (int j = 0; j < 8; ++j) {
                int k = kt * 32 + qq * 8 + j;
                v[j] = (k < 48) ? (__bf16)tmp[j] : (__bf16)0.0f;
            }
        } else {
            const int g = f - 24, kt = g / 3, nt = g % 3;
            const float* s2 = cw2 + (size_t)m * (192 * 48);
            #pragma unroll
            for (int j = 0; j < 8; ++j)
                tmp[j] = s2[(kt * 32 + qq * 8 + j) * 48 + nt * 16 + cc];
            #pragma unroll
            for (int j = 0; j < 8; ++j) v[j] = (__bf16)tmp[j];
        }
        dst = wchk + (size_t)m * 21504 + (f * 64 + l) * 8;
    } else {
        const int tsk = wid - MM * 42;
        const int nv = tsk / 15, f = tsk % 15;
        if (f < 7) {
            const float* s1 = vw1 + (size_t)nv * (25 * 100);
            const int n = f * 16 + cc, nc = min(n, 99);
            #pragma unroll
            for (int j = 0; j < 8; ++j) {
                int k = qq * 8 + j;
                tmp[j] = s1[min(k, 24) * 100 + nc];
            }
            #pragma unroll
            for (int j = 0; j < 8; ++j) {
                int k = qq * 8 + j;
                v[j] = (k < 25 && n < 100) ? (__bf16)tmp[j] : (__bf16)0.0f;
            }
        } else {
            const int g = f - 7, kt = g >> 1, nt = g & 1;
            const float* s2 = vw2 + (size_t)nv * (100 * 25);
            const int n = nt * 16 + cc, nc = min(n, 24);
            #pragma unroll
            for (int j = 0; j < 8; ++j) {
                int k = kt * 32 + qq * 8 + j;
                tmp[j] = s2[min(k, 99) * 25 + nc];
            }
            #pragma unroll
            for (int j = 0; j < 8; ++j) {
                int k = kt * 32 + qq * 8 + j;
                v[j] = (k < 100 && n < 25) ? (__bf16)tmp[j] : (__bf16)0.0f;
            }
        }
        dst = wvar + (size_t)nv * 7680 + (f * 64 + l) * 8;
    }
    *(bf16x8*)dst = v;
}

// ---------------------------------------------------------------------------
// Check MLP. Weights staged to LDS ONCE per block (43 KB, conflict-free b128
// copies, one barrier), then wave-independent. Hidden dim processed in 3
// chunks of 64 cols -> per-wave scratch only 2.25 KB -> 51 KB LDS total,
// 3 blocks/CU. Weight L3 traffic: 44 MB/dispatch (was 352).
// MFMA 16x16x32 bf16: A[m=l&15][k=q*8+j], B[k=q*8+j][n=l&15],
// C/D[row=q*4+r][col=l&15]
// ---------------------------------------------------------------------------
__global__ __launch_bounds__(256, 3)
void chk_kernel(const __bf16* __restrict__ wchk,
                const float* __restrict__ b1g, const float* __restrict__ b2g,
                const int* __restrict__ syndromes,
                const int* __restrict__ v2c_gather,
                const __bf16* __restrict__ v2c, __bf16* __restrict__ c2v)
{
    const int m = blockIdx.x;
    const int tid = threadIdx.x;
    const int w = tid >> 6, l = tid & 63, q = l >> 4, c = l & 15;

    __shared__ __align__(16) __bf16 wlds[21504];     // 42 fragments, 43 KB
    __shared__ __align__(16) __bf16 scr[4 * 1152];   // per-wave 16x72 chunk/Y

    // stage prepped weights: 16B stride-1 copies, conflict-free
    {
        const __bf16* src = wchk + (size_t)m * 21504;
        for (int i = tid; i < 2688; i += 256)
            *(u32x4*)(wlds + i * 8) = *(const u32x4*)(src + i * 8);
    }

    // hoisted per-lane biases / syndrome signs / edge ids (global, cached)
    float b1v[12], b2v[3], sg[8];
    #pragma unroll
    for (int nt = 0; nt < 12; ++nt) b1v[nt] = b1g[(size_t)m * 192 + nt * 16 + c];
    #pragma unroll
    for (int nt = 0; nt < 3; ++nt)  b2v[nt] = b2g[(size_t)m * 48 + nt * 16 + c];
    #pragma unroll
    for (int t2 = 0; t2 < 2; ++t2)
        #pragma unroll
        for (int r = 0; r < 4; ++r) {
            int row = t2 * 64 + w * 16 + q * 4 + r;
            sg[t2 * 4 + r] = (float)(1 - 2 * syndromes[(size_t)row * MM + m]);
        }
    const int e0 = v2c_gather[m * 6 + q];
    const int e1 = (q < 2) ? v2c_gather[m * 6 + 4 + q] : 0;

    __syncthreads();

    __bf16* myc = scr + w * 1152;   // 16x72 (H-chunk, pitch 72) / 16x56 (Y, pitch 56)

    for (int t2 = 0; t2 < 2; ++t2) {
        const int bt = t2 * 64 + w * 16;

        bf16x8 a0 = *(const bf16x8*)(v2c + ((size_t)e0 * BB + bt + c) * 8);
        bf16x8 a1;
        #pragma unroll
        for (int j = 0; j < 8; ++j) a1[j] = (__bf16)0.0f;
        if (q < 2) a1 = *(const bf16x8*)(v2c + ((size_t)e1 * BB + bt + c) * 8);

        f32x4 acc2[3];
        #pragma unroll
        for (int nt = 0; nt < 3; ++nt) acc2[nt] = (f32x4){0.f, 0.f, 0.f, 0.f};

        #pragma unroll
        for (int ch = 0; ch < 3; ++ch) {
            // ---- layer 1, hidden cols [ch*64, ch*64+64) ----
            f32x4 acc[4];
            #pragma unroll
            for (int lnt = 0; lnt < 4; ++lnt) {
                int nt = ch * 4 + lnt;
                bf16x8 bf0 = *(const bf16x8*)(wlds + (nt * 64 + l) * 8);
                bf16x8 bf1 = *(const bf16x8*)(wlds + ((12 + nt) * 64 + l) * 8);
                f32x4 z = {0.f, 0.f, 0.f, 0.f};
                z = __builtin_amdgcn_mfma_f32_16x16x32_bf16(a0, bf0, z, 0, 0, 0);
                z = __builtin_amdgcn_mfma_f32_16x16x32_bf16(a1, bf1, z, 0, 0, 0);
                acc[lnt] = z;
            }
            // bias + GELU -> chunk (C-layout -> [row][local k])
            #pragma unroll
            for (int lnt = 0; lnt < 4; ++lnt) {
                #pragma unroll
                for (int r = 0; r < 4; ++r) {
                    int row = q * 4 + r;
                    myc[row * 72 + lnt * 16 + c] =
                        (__bf16)gelu_fast(acc[lnt][r] + b1v[ch * 4 + lnt]);
                }
            }
            wave_lds_fence();
            // ---- layer 2 partial: kt = ch*2 + {0,1} ----
            #pragma unroll
            for (int ktl = 0; ktl < 2; ++ktl) {
                bf16x8 aF = *(const bf16x8*)(myc + c * 72 + ktl * 32 + q * 8);
                #pragma unroll
                for (int nt = 0; nt < 3; ++nt) {
                    bf16x8 bfr = *(const bf16x8*)(wlds +
                        ((24 + (ch * 2 + ktl) * 3 + nt) * 64 + l) * 8);
                    acc2[nt] = __builtin_amdgcn_mfma_f32_16x16x32_bf16(aF, bfr, acc2[nt], 0, 0, 0);
                }
            }
            wave_lds_fence();   // chunk reads done before next chunk's writes
        }

        // ---- epilogue: bias + syndrome sign -> Y (pitch 56) ----
        #pragma unroll
        for (int nt = 0; nt < 3; ++nt) {
            #pragma unroll
            for (int r = 0; r < 4; ++r) {
                int row = q * 4 + r;
                myc[row * 56 + nt * 16 + c] =
                    (__bf16)((acc2[nt][r] + b2v[nt]) * sg[t2 * 4 + r]);
            }
        }
        wave_lds_fence();

        // coalesced 16B message stores: 96 chunks (s=0..5, row=0..15)
        {
            int s = l >> 4, row = l & 15;
            u32x4 vv = *(const u32x4*)(myc + row * 56 + s * 8);
            *(u32x4*)(c2v + ((size_t)(m * 6 + s) * BB + bt + row) * 8) = vv;
            if (l < 32) {
                int s2 = 4 + (l >> 4), row2 = l & 15;
                u32x4 v2 = *(const u32x4*)(myc + row2 * 56 + s2 * 8);
                *(u32x4*)(c2v + ((size_t)(m * 6 + s2) * BB + bt + row2) * 8) = v2;
            }
        }
        wave_lds_fence();   // Y reads done before next t2 overwrites scratch
    }
}

// ---------------------------------------------------------------------------
// Variable MLP. Weights staged to LDS once (15 KB), wave-independent after.
// LDS 37.9 KB -> 4 blocks/CU. Weight L3 traffic: 31 MB/dispatch (was 246).
// ---------------------------------------------------------------------------
__global__ __launch_bounds__(256, 4)
void var_kernel(const __bf16* __restrict__ wvar,
                const float* __restrict__ b1g, const float* __restrict__ b2g,
                const int* __restrict__ c2v_gather, const float* __restrict__ prior,
                const __bf16* __restrict__ c2v, __bf16* __restrict__ v2c,
                float* __restrict__ llr_out, int last)
{
    const int nv = blockIdx.x;
    const int tid = threadIdx.x;
    const int w = tid >> 6, l = tid & 63, q = l >> 4, c = l & 15;

    __shared__ __align__(16) __bf16 wlds[7680];      // 15 fragments
    __shared__ __align__(16) __bf16 hb[4 * 2816];    // per-wave 16x136 H + 16x40 Y

    {
        const __bf16* src = wvar + (size_t)nv * 7680;
        for (int i = tid; i < 960; i += 256)
            *(u32x4*)(wlds + i * 8) = *(const u32x4*)(src + i * 8);
    }

    __bf16* myh = hb + w * 2816;
    __bf16* myy = myh + 2176;

    // zero H pad cols 112..127 (layer-2 A reads them; 0*stale-NaN hazard)
    {
        int r = l >> 2, g = l & 3;
        *(u32x2*)(myh + r * 136 + 112 + g * 4) = (u32x2){0, 0};
    }

    float b1v[7], b2v[2];
    #pragma unroll
    for (int nt = 0; nt < 7; ++nt) {
        int col = nt * 16 + c;
        b1v[nt] = (col < 100) ? b1g[(size_t)nv * 100 + col] : 0.0f;
    }
    #pragma unroll
    for (int nt = 0; nt < 2; ++nt) {
        int col = nt * 16 + c;
        b2v[nt] = (col < 25) ? b2g[(size_t)nv * 25 + col] : 0.0f;
    }
    const __bf16 prbf = (__bf16)prior[nv];
    const int ep = (q < 3) ? c2v_gather[nv * 3 + q] : 0;

    __syncthreads();

    for (int t2 = 0; t2 < 2; ++t2) {
        const int bt = t2 * 64 + w * 16;

        bf16x8 a;
        #pragma unroll
        for (int j = 0; j < 8; ++j) a[j] = (__bf16)0.0f;
        if (q < 3) a = *(const bf16x8*)(c2v + ((size_t)ep * BB + bt + c) * 8);
        else       a[0] = prbf;

        f32x4 acc[7];
        #pragma unroll
        for (int nt = 0; nt < 7; ++nt) {
            bf16x8 bfr = *(const bf16x8*)(wlds + (nt * 64 + l) * 8);
            f32x4 z = {0.f, 0.f, 0.f, 0.f};
            acc[nt] = __builtin_amdgcn_mfma_f32_16x16x32_bf16(a, bfr, z, 0, 0, 0);
        }

        #pragma unroll
        for (int nt = 0; nt < 7; ++nt) {
            #pragma unroll
            for (int r = 0; r < 4; ++r) {
                int row = q * 4 + r;
                myh[row * 136 + nt * 16 + c] = (__bf16)gelu_fast(acc[nt][r] + b1v[nt]);
            }
        }
        wave_lds_fence();

        f32x4 acc2[2];
        acc2[0] = (f32x4){0.f, 0.f, 0.f, 0.f};
        acc2[1] = (f32x4){0.f, 0.f, 0.f, 0.f};
        #pragma unroll
        for (int kt = 0; kt < 4; ++kt) {
            bf16x8 a2 = *(const bf16x8*)(myh + c * 136 + kt * 32 + q * 8);
            #pragma unroll
            for (int nt = 0; nt < 2; ++nt) {
                bf16x8 bfr = *(const bf16x8*)(wlds + ((7 + kt * 2 + nt) * 64 + l) * 8);
                acc2[nt] = __builtin_amdgcn_mfma_f32_16x16x32_bf16(a2, bfr, acc2[nt], 0, 0, 0);
            }
        }
        wave_lds_fence();

        #pragma unroll
        for (int nt = 0; nt < 2; ++nt) {
            #pragma unroll
            for (int r = 0; r < 4; ++r) {
                int row = q * 4 + r, col = nt * 16 + c;
                float yv = acc2[nt][r] + b2v[nt];
                if (col < 24) myy[row * 40 + col] = (__bf16)yv;
                else if (col == 24) llr_out[(size_t)(bt + row) * NN + nv] = yv;
            }
        }
        wave_lds_fence();

        if (!last && l < 48) {
            int s = l >> 4, row = l & 15;
            u32x4 vv = *(const u32x4*)(myy + row * 40 + s * 8);
            *(u32x4*)(v2c + ((size_t)(nv * 3 + s) * BB + bt + row) * 8) = vv;
        }
        wave_lds_fence();
    }
}

extern "C" void kernel_launch(void* const* d_in, const int* in_sizes, int n_in,
                              void* d_out, int out_size, void* d_ws, size_t ws_size,
                              hipStream_t stream) {
    const int*   syndromes = (const int*)  d_in[0];
    const float* prior_llr = (const float*)d_in[1];
    const float* chk_w1    = (const float*)d_in[2];
    const float* chk_b1    = (const float*)d_in[3];
    const float* chk_w2    = (const float*)d_in[4];
    const float* chk_b2    = (const float*)d_in[5];
    const float* var_w1    = (const float*)d_in[6];
    const float* var_b1    = (const float*)d_in[7];
    const float* var_w2    = (const float*)d_in[8];
    const float* var_b2    = (const float*)d_in[9];
    const int*   c2v_g     = (const int*)  d_in[11];
    const int*   v2c_g     = (const int*)  d_in[12];

    float* out = (float*)d_out;

    __bf16* v2c  = (__bf16*)d_ws;                          // 6144*128*8
    __bf16* c2v  = v2c + (size_t)EE * BB * 8;              // 6144*128*8
    __bf16* wchk = c2v + (size_t)EE * BB * 8;              // 1024*21504
    __bf16* wvar = wchk + (size_t)MM * 21504;              // 2048*7680

    prep_all<<<(MM * 42 + NN * 15) / 4, 256, 0, stream>>>(chk_w1, chk_w2,
                                                          var_w1, var_w2,
                                                          wchk, wvar);
    init_kernel<<<EE * BB / 256, 256, 0, stream>>>(prior_llr, v2c);

    for (int t = 0; t < TT; ++t) {
        chk_kernel<<<MM, 256, 0, stream>>>(wchk, chk_b1, chk_b2,
                                           syndromes, v2c_g, v2c, c2v);
        var_kernel<<<NN, 256, 0, stream>>>(wvar, var_b1, var_b2,
                                           c2v_g, prior_llr, c2v, v2c,
                                           out + (size_t)t * BB * NN,
                                           (t == TT - 1) ? 1 : 0);
    }
}